// Round 1
// baseline (2164.621 us; speedup 1.0000x reference)
//
#include <hip/hip_runtime.h>

#define HEADS 4
#define HID 32
#define DCH 128            // HEADS*HID
#define OUTC 10
#define NSLOPE 0.2f

// ---- per-node attention logits: asrc[n,h] = <W[x[n]], att_src[h]> (conv1: gather W1 row by class)
__global__ void k_node_att1(const int* __restrict__ x, const float* __restrict__ W,
                            const float* __restrict__ att_src, const float* __restrict__ att_dst,
                            float* __restrict__ asrc, float* __restrict__ adst, int N) {
    int gid = blockIdx.x * blockDim.x + threadIdx.x;
    if (gid >= N * HEADS) return;
    int n = gid >> 2, h = gid & 3;
    const float* w  = W + (size_t)x[n] * DCH + h * HID;
    const float* as = att_src + h * HID;
    const float* ad = att_dst + h * HID;
    float s1 = 0.f, s2 = 0.f;
#pragma unroll
    for (int c = 0; c < HID; c++) { float wv = w[c]; s1 = fmaf(wv, as[c], s1); s2 = fmaf(wv, ad[c], s2); }
    asrc[gid] = s1; adst[gid] = s2;
}

// ---- conv3 variant: feature rows come from hp (dense [N,128])
__global__ void k_node_att3(const float* __restrict__ hp,
                            const float* __restrict__ att_src, const float* __restrict__ att_dst,
                            float* __restrict__ asrc, float* __restrict__ adst, int N) {
    int gid = blockIdx.x * blockDim.x + threadIdx.x;
    if (gid >= N * HEADS) return;
    int n = gid >> 2, h = gid & 3;
    const float* w  = hp + (size_t)n * DCH + h * HID;
    const float* as = att_src + h * HID;
    const float* ad = att_dst + h * HID;
    float s1 = 0.f, s2 = 0.f;
#pragma unroll
    for (int c = 0; c < HID; c++) { float wv = w[c]; s1 = fmaf(wv, as[c], s1); s2 = fmaf(wv, ad[c], s2); }
    asrc[gid] = s1; adst[gid] = s2;
}

// ---- pass A: denom[d,h] += exp(leakyrelu(asrc[s,h]+adst[d,h]))   (self-loops implicit: e>=E -> (i,i))
__global__ void k_edge_denom(const int* __restrict__ esrc, const int* __restrict__ edst,
                             int E, int N,
                             const float* __restrict__ asrc, const float* __restrict__ adst,
                             float* __restrict__ denom) {
    int e = blockIdx.x * blockDim.x + threadIdx.x;
    int EP = E + N;
    if (e >= EP) return;
    int s, d;
    if (e < E) { s = esrc[e]; d = edst[e]; } else { s = e - E; d = s; }
#pragma unroll
    for (int h = 0; h < HEADS; h++) {
        float ev = asrc[s * HEADS + h] + adst[d * HEADS + h];
        ev = ev >= 0.f ? ev : NSLOPE * ev;
        atomicAdd(&denom[d * HEADS + h], expf(ev));
    }
}

// ---- pass B conv1: out[d,:] += exp(e) * W1[x[s],:]   (32 lanes/edge, 4 heads each)
__global__ void k_edge_accum1(const int* __restrict__ esrc, const int* __restrict__ edst,
                              int E, int N, const int* __restrict__ x,
                              const float* __restrict__ W1,
                              const float* __restrict__ asrc, const float* __restrict__ adst,
                              float* __restrict__ out) {
    int gid = blockIdx.x * blockDim.x + threadIdx.x;
    int lane = gid & 31;
    int e = gid >> 5;
    int EP = E + N;
    if (e >= EP) return;
    int s, d;
    if (e < E) { s = esrc[e]; d = edst[e]; } else { s = e - E; d = s; }
    const float* w = W1 + (size_t)x[s] * DCH;
#pragma unroll
    for (int h = 0; h < HEADS; h++) {
        float ev = asrc[s * HEADS + h] + adst[d * HEADS + h];
        ev = ev >= 0.f ? ev : NSLOPE * ev;
        float ex = expf(ev);
        atomicAdd(&out[(size_t)d * DCH + h * HID + lane], ex * w[h * HID + lane]);
    }
}

// ---- pass B conv3: out[d,:] += exp(e) * hp[s,:]
__global__ void k_edge_accum3(const int* __restrict__ esrc, const int* __restrict__ edst,
                              int E, int N,
                              const float* __restrict__ hp,
                              const float* __restrict__ asrc, const float* __restrict__ adst,
                              float* __restrict__ out) {
    int gid = blockIdx.x * blockDim.x + threadIdx.x;
    int lane = gid & 31;
    int e = gid >> 5;
    int EP = E + N;
    if (e >= EP) return;
    int s, d;
    if (e < E) { s = esrc[e]; d = edst[e]; } else { s = e - E; d = s; }
    const float* w = hp + (size_t)s * DCH;
#pragma unroll
    for (int h = 0; h < HEADS; h++) {
        float ev = asrc[s * HEADS + h] + adst[d * HEADS + h];
        ev = ev >= 0.f ? ev : NSLOPE * ev;
        float ex = expf(ev);
        atomicAdd(&out[(size_t)d * DCH + h * HID + lane], ex * w[h * HID + lane]);
    }
}

// ---- normalize + bias + relu (conv1 epilogue), in place
__global__ void k_norm_relu(float* __restrict__ hbuf, const float* __restrict__ denom,
                            const float* __restrict__ bias, int N) {
    int gid = blockIdx.x * blockDim.x + threadIdx.x;
    if (gid >= N * DCH) return;
    int n = gid >> 7, c = gid & (DCH - 1), h = c >> 5;
    float v = hbuf[gid] / denom[n * HEADS + h] + bias[c];
    hbuf[gid] = v > 0.f ? v : 0.f;
}

// ---- hp3 = h1 @ W3 : one block per row, 128 threads
__global__ void k_gemm128(const float* __restrict__ A, const float* __restrict__ W,
                          float* __restrict__ C, int N) {
    __shared__ float sh[DCH];
    int n = blockIdx.x;
    int t = threadIdx.x;
    sh[t] = A[(size_t)n * DCH + t];
    __syncthreads();
    float acc = 0.f;
#pragma unroll 8
    for (int k = 0; k < DCH; k++) acc = fmaf(sh[k], W[k * DCH + t], acc);
    C[(size_t)n * DCH + t] = acc;
}

// ---- conv3 epilogue + mean-pool accumulate
__global__ void k_norm_pool(const float* __restrict__ hbuf, const float* __restrict__ denom,
                            const float* __restrict__ bias, const int* __restrict__ batch,
                            float* __restrict__ pool, int N) {
    int gid = blockIdx.x * blockDim.x + threadIdx.x;
    if (gid >= N * DCH) return;
    int n = gid >> 7, c = gid & (DCH - 1), h = c >> 5;
    float v = hbuf[gid] / denom[n * HEADS + h] + bias[c];
    atomicAdd(&pool[(size_t)batch[n] * DCH + c], v);
}

__global__ void k_cnt(const int* __restrict__ batch, float* __restrict__ cnt, int N) {
    int n = blockIdx.x * blockDim.x + threadIdx.x;
    if (n >= N) return;
    atomicAdd(&cnt[batch[n]], 1.0f);
}

// ---- classifier: out[g,o] = (pool[g,:]/cnt[g]) . lin_w[:,o] + lin_b[o]
__global__ void k_final(const float* __restrict__ pool, const float* __restrict__ cnt,
                        const float* __restrict__ lw, const float* __restrict__ lb,
                        float* __restrict__ out, int G) {
    int gid = blockIdx.x * blockDim.x + threadIdx.x;
    if (gid >= G * OUTC) return;
    int g = gid / OUTC, o = gid % OUTC;
    float inv = 1.0f / fmaxf(cnt[g], 1.0f);
    float acc = 0.f;
#pragma unroll 8
    for (int k = 0; k < DCH; k++) acc = fmaf(pool[g * DCH + k] * inv, lw[k * OUTC + o], acc);
    out[gid] = acc + lb[o];
}

extern "C" void kernel_launch(void* const* d_in, const int* in_sizes, int n_in,
                              void* d_out, int out_size, void* d_ws, size_t ws_size,
                              hipStream_t stream) {
    const int*   x    = (const int*)d_in[0];
    const int*   eidx = (const int*)d_in[1];
    const int*   batch= (const int*)d_in[2];
    const float* W1   = (const float*)d_in[3];
    const float* as1  = (const float*)d_in[4];
    const float* ad1  = (const float*)d_in[5];
    const float* b1   = (const float*)d_in[6];
    const float* W3   = (const float*)d_in[7];
    const float* as3  = (const float*)d_in[8];
    const float* ad3  = (const float*)d_in[9];
    const float* b3   = (const float*)d_in[10];
    const float* lw   = (const float*)d_in[11];
    const float* lb   = (const float*)d_in[12];
    float* out = (float*)d_out;

    const int N  = in_sizes[0];
    const int E  = in_sizes[1] / 2;
    const int G  = out_size / OUTC;
    const int EP = E + N;
    const int* esrc = eidx;
    const int* edst = eidx + E;

    // workspace layout (floats)
    float* bufA   = (float*)d_ws;                    // [N,128]  h1, later out3
    float* bufB   = bufA   + (size_t)N * DCH;        // [N,128]  hproj3
    float* asrc1  = bufB   + (size_t)N * DCH;        // [N,4]
    float* adst1  = asrc1  + (size_t)N * HEADS;
    float* asrc3  = adst1  + (size_t)N * HEADS;
    float* adst3  = asrc3  + (size_t)N * HEADS;
    float* denom1 = adst3  + (size_t)N * HEADS;
    float* denom3 = denom1 + (size_t)N * HEADS;
    float* pool   = denom3 + (size_t)N * HEADS;      // [G,128]
    float* cnt    = pool   + (size_t)G * DCH;        // [G]

    const int BS = 256;

    // zero accumulators (harness does not re-poison between replays)
    hipMemsetAsync(denom1, 0, (size_t)N * HEADS * sizeof(float), stream);
    hipMemsetAsync(denom3, 0, (size_t)N * HEADS * sizeof(float), stream);
    hipMemsetAsync(bufA,   0, (size_t)N * DCH * sizeof(float), stream);
    hipMemsetAsync(pool,   0, (size_t)(G * DCH + G) * sizeof(float), stream);

    // ---- conv1 ----
    k_node_att1<<<(N * HEADS + BS - 1) / BS, BS, 0, stream>>>(x, W1, as1, ad1, asrc1, adst1, N);
    k_edge_denom<<<(EP + BS - 1) / BS, BS, 0, stream>>>(esrc, edst, E, N, asrc1, adst1, denom1);
    {
        long long tot = (long long)EP * 32;
        k_edge_accum1<<<(int)((tot + BS - 1) / BS), BS, 0, stream>>>(esrc, edst, E, N, x, W1, asrc1, adst1, bufA);
    }
    k_norm_relu<<<(N * DCH + BS - 1) / BS, BS, 0, stream>>>(bufA, denom1, b1, N);

    // ---- conv3 ----
    k_gemm128<<<N, DCH, 0, stream>>>(bufA, W3, bufB, N);
    k_node_att3<<<(N * HEADS + BS - 1) / BS, BS, 0, stream>>>(bufB, as3, ad3, asrc3, adst3, N);
    hipMemsetAsync(bufA, 0, (size_t)N * DCH * sizeof(float), stream);   // reuse h1 buffer as out3
    k_edge_denom<<<(EP + BS - 1) / BS, BS, 0, stream>>>(esrc, edst, E, N, asrc3, adst3, denom3);
    {
        long long tot = (long long)EP * 32;
        k_edge_accum3<<<(int)((tot + BS - 1) / BS), BS, 0, stream>>>(esrc, edst, E, N, bufB, asrc3, adst3, bufA);
    }

    // ---- epilogue + pool + classifier ----
    k_norm_pool<<<(N * DCH + BS - 1) / BS, BS, 0, stream>>>(bufA, denom3, b3, batch, pool, N);
    k_cnt<<<(N + BS - 1) / BS, BS, 0, stream>>>(batch, cnt, N);
    k_final<<<(G * OUTC + BS - 1) / BS, BS, 0, stream>>>(pool, cnt, lw, lb, out, G);
}

// Round 2
// 951.096 us; speedup vs baseline: 2.2759x; 2.2759x over previous
//
#include <hip/hip_runtime.h>

#define HEADS 4
#define HID 32
#define DCH 128            // HEADS*HID
#define OUTC 10
#define NSLOPE 0.2f

#define SCAN_T 256
#define SCAN_PT 8
#define SCAN_ELEMS (SCAN_T * SCAN_PT)   // 2048 elements per scan block

// ---- per-node attention logits (conv1: W1 row gathered by class id)
__global__ void k_node_att1(const int* __restrict__ x, const float* __restrict__ W,
                            const float* __restrict__ att_src, const float* __restrict__ att_dst,
                            float* __restrict__ asrc, float* __restrict__ adst, int N) {
    int gid = blockIdx.x * blockDim.x + threadIdx.x;
    if (gid >= N * HEADS) return;
    int n = gid >> 2, h = gid & 3;
    const float* w  = W + (size_t)x[n] * DCH + h * HID;
    const float* as = att_src + h * HID;
    const float* ad = att_dst + h * HID;
    float s1 = 0.f, s2 = 0.f;
#pragma unroll
    for (int c = 0; c < HID; c++) { float wv = w[c]; s1 = fmaf(wv, as[c], s1); s2 = fmaf(wv, ad[c], s2); }
    asrc[gid] = s1; adst[gid] = s2;
}

// ---- conv3 variant: feature rows from dense hp [N,128]
__global__ void k_node_att3(const float* __restrict__ hp,
                            const float* __restrict__ att_src, const float* __restrict__ att_dst,
                            float* __restrict__ asrc, float* __restrict__ adst, int N) {
    int gid = blockIdx.x * blockDim.x + threadIdx.x;
    if (gid >= N * HEADS) return;
    int n = gid >> 2, h = gid & 3;
    const float* w  = hp + (size_t)n * DCH + h * HID;
    const float* as = att_src + h * HID;
    const float* ad = att_dst + h * HID;
    float s1 = 0.f, s2 = 0.f;
#pragma unroll
    for (int c = 0; c < HID; c++) { float wv = w[c]; s1 = fmaf(wv, as[c], s1); s2 = fmaf(wv, ad[c], s2); }
    asrc[gid] = s1; adst[gid] = s2;
}

// ================= CSR build (dst-major) =================
__global__ void k_deg(const int* __restrict__ edst, int E, int N, int* __restrict__ deg) {
    int e = blockIdx.x * blockDim.x + threadIdx.x;
    int EP = E + N;
    if (e >= EP) return;
    int d = (e < E) ? edst[e] : (e - E);     // self-loops appended
    atomicAdd(&deg[d], 1);
}

// block-local inclusive scan of deg -> rowstart[i+1]; block totals -> bsum
__global__ void k_scan_a(const int* __restrict__ deg, int* __restrict__ rowstart,
                         int* __restrict__ bsum, int N) {
    __shared__ int sh[SCAN_T];
    int base = blockIdx.x * SCAN_ELEMS;
    int t = threadIdx.x;
    int v[SCAN_PT];
    int s = 0;
#pragma unroll
    for (int i = 0; i < SCAN_PT; i++) {
        int idx = base + t * SCAN_PT + i;
        int dv = (idx < N) ? deg[idx] : 0;
        s += dv; v[i] = s;                    // thread-local running inclusive
    }
    sh[t] = s;
    __syncthreads();
    for (int off = 1; off < SCAN_T; off <<= 1) {
        int add = (t >= off) ? sh[t - off] : 0;
        __syncthreads();
        sh[t] += add;
        __syncthreads();
    }
    int excl = (t > 0) ? sh[t - 1] : 0;
#pragma unroll
    for (int i = 0; i < SCAN_PT; i++) {
        int idx = base + t * SCAN_PT + i;
        if (idx < N) rowstart[idx + 1] = v[i] + excl;
    }
    if (t == SCAN_T - 1) bsum[blockIdx.x] = sh[t];
}

// single-block exclusive scan of bsum (nb <= 1024)
__global__ void k_scan_b(int* __restrict__ bsum, int nb) {
    __shared__ int sh[1024];
    int t = threadIdx.x;
    sh[t] = (t < nb) ? bsum[t] : 0;
    __syncthreads();
    for (int off = 1; off < 1024; off <<= 1) {
        int add = (t >= off) ? sh[t - off] : 0;
        __syncthreads();
        sh[t] += add;
        __syncthreads();
    }
    if (t < nb) bsum[t] = (t > 0) ? sh[t - 1] : 0;
}

__global__ void k_scan_c(int* __restrict__ rowstart, const int* __restrict__ boff, int N) {
    int i = blockIdx.x * blockDim.x + threadIdx.x;
    if (i >= N) return;
    rowstart[i + 1] += boff[i / SCAN_ELEMS];
    if (i == 0) rowstart[0] = 0;
}

__global__ void k_scatter(const int* __restrict__ esrc, const int* __restrict__ edst,
                          int E, int N, const int* __restrict__ rowstart,
                          int* __restrict__ cursor, int* __restrict__ csr_src) {
    int e = blockIdx.x * blockDim.x + threadIdx.x;
    int EP = E + N;
    if (e >= EP) return;
    int s, d;
    if (e < E) { s = esrc[e]; d = edst[e]; } else { s = e - E; d = s; }
    int pos = rowstart[d] + atomicAdd(&cursor[d], 1);
    csr_src[pos] = s;
}

// ================= conv1 gather: one block per dst node =================
// one-hot factorization: accumulate per-(head,class) exp-weights, then
// h1[d, h*32+j] = (sum_k acc[h][k] * W1[k, h*32+j]) / denom + b ; ReLU
__global__ __launch_bounds__(128) void k_gather1(
        const int* __restrict__ rowstart, const int* __restrict__ csr_src,
        const int* __restrict__ x, const float* __restrict__ W1,
        const float* __restrict__ asrc, const float* __restrict__ adst,
        const float* __restrict__ bias, float* __restrict__ outh, int N) {
    __shared__ float lds[HEADS][HID + 1];
    int d = blockIdx.x;
    int c = threadIdx.x;
    int h = c >> 5, k = c & 31;
    float adst_h = adst[d * HEADS + h];
    int p0 = rowstart[d], p1 = rowstart[d + 1];
    float acc = 0.f;
    for (int p = p0; p < p1; p++) {
        int s = csr_src[p];
        float ev = asrc[s * HEADS + h] + adst_h;
        ev = ev >= 0.f ? ev : NSLOPE * ev;
        float ex = __expf(ev);
        if (x[s] == k) acc += ex;
    }
    lds[h][k] = acc;
    __syncthreads();
    float denom = 0.f, dot = 0.f;
#pragma unroll
    for (int kk = 0; kk < HID; kk++) {
        float a = lds[h][kk];
        denom += a;
        dot = fmaf(a, W1[kk * DCH + c], dot);
    }
    float v = dot / denom + bias[c];
    outh[(size_t)d * DCH + c] = v > 0.f ? v : 0.f;
}

// ================= conv3 gather =================
__global__ __launch_bounds__(128) void k_gather3(
        const int* __restrict__ rowstart, const int* __restrict__ csr_src,
        const float* __restrict__ hp, const float* __restrict__ asrc,
        const float* __restrict__ adst, const float* __restrict__ bias,
        float* __restrict__ outh, int N) {
    int d = blockIdx.x;
    int c = threadIdx.x;
    int h = c >> 5;
    float adst_h = adst[d * HEADS + h];
    int p0 = rowstart[d], p1 = rowstart[d + 1];
    float acc = 0.f, den = 0.f;
    for (int p = p0; p < p1; p++) {
        int s = csr_src[p];
        float ev = asrc[s * HEADS + h] + adst_h;
        ev = ev >= 0.f ? ev : NSLOPE * ev;
        float ex = __expf(ev);
        den += ex;
        acc = fmaf(ex, hp[(size_t)s * DCH + c], acc);
    }
    outh[(size_t)d * DCH + c] = acc / den + bias[c];
}

// ---- hp3 = h1 @ W3 : one block per row, 128 threads
__global__ void k_gemm128(const float* __restrict__ A, const float* __restrict__ W,
                          float* __restrict__ C, int N) {
    __shared__ float sh[DCH];
    int n = blockIdx.x;
    int t = threadIdx.x;
    sh[t] = A[(size_t)n * DCH + t];
    __syncthreads();
    float acc = 0.f;
#pragma unroll 8
    for (int k = 0; k < DCH; k++) acc = fmaf(sh[k], W[k * DCH + t], acc);
    C[(size_t)n * DCH + t] = acc;
}

// ---- graph boundaries from sorted batch: gstart[g] = first node with batch>=g
__global__ void k_bounds(const int* __restrict__ batch, int* __restrict__ gstart, int N, int G) {
    int n = blockIdx.x * blockDim.x + threadIdx.x;
    if (n > N) return;
    if (n == 0) {
        int b0 = batch[0];
        for (int g = 0; g <= b0; g++) gstart[g] = 0;
        return;
    }
    if (n == N) {
        int bl = batch[N - 1];
        for (int g = bl + 1; g <= G; g++) gstart[g] = N;
        return;
    }
    int b = batch[n], bp = batch[n - 1];
    for (int g = bp + 1; g <= b; g++) gstart[g] = n;
}

// ---- mean-pool + classifier, one block per graph
__global__ __launch_bounds__(128) void k_pool_final(
        const float* __restrict__ h, const int* __restrict__ gstart,
        const float* __restrict__ lw, const float* __restrict__ lb,
        float* __restrict__ out, int G) {
    __shared__ float pooled[DCH];
    int g = blockIdx.x, c = threadIdx.x;
    int n0 = gstart[g], n1 = gstart[g + 1];
    float s = 0.f;
    for (int n = n0; n < n1; n++) s += h[(size_t)n * DCH + c];
    float cntf = (float)(n1 - n0);
    pooled[c] = s / fmaxf(cntf, 1.f);
    __syncthreads();
    if (c < OUTC) {
        float acc = lb[c];
#pragma unroll 8
        for (int k = 0; k < DCH; k++) acc = fmaf(pooled[k], lw[k * OUTC + c], acc);
        out[g * OUTC + c] = acc;
    }
}

extern "C" void kernel_launch(void* const* d_in, const int* in_sizes, int n_in,
                              void* d_out, int out_size, void* d_ws, size_t ws_size,
                              hipStream_t stream) {
    const int*   x    = (const int*)d_in[0];
    const int*   eidx = (const int*)d_in[1];
    const int*   batch= (const int*)d_in[2];
    const float* W1   = (const float*)d_in[3];
    const float* as1  = (const float*)d_in[4];
    const float* ad1  = (const float*)d_in[5];
    const float* b1   = (const float*)d_in[6];
    const float* W3   = (const float*)d_in[7];
    const float* as3  = (const float*)d_in[8];
    const float* ad3  = (const float*)d_in[9];
    const float* b3   = (const float*)d_in[10];
    const float* lw   = (const float*)d_in[11];
    const float* lb   = (const float*)d_in[12];
    float* out = (float*)d_out;

    const int N  = in_sizes[0];
    const int E  = in_sizes[1] / 2;
    const int G  = out_size / OUTC;
    const int EP = E + N;
    const int* esrc = eidx;
    const int* edst = eidx + E;

    // ---- workspace layout ----
    float* bufA    = (float*)d_ws;                     // [N,128] h1, later out3
    float* bufB    = bufA + (size_t)N * DCH;           // [N,128] hproj3
    float* asrc_b  = bufB + (size_t)N * DCH;           // [N,4]  (reused conv1->conv3)
    float* adst_b  = asrc_b + (size_t)N * HEADS;       // [N,4]
    int*   deg     = (int*)(adst_b + (size_t)N * HEADS); // [N] degree, then cursor
    int*   rowstart= deg + N;                          // [N+1]
    int*   bsum    = rowstart + (N + 1);               // [<=1024]
    int*   csr_src = bsum + 1024;                      // [EP]
    int*   gstart  = csr_src + EP;                     // [G+1]

    const int BS = 256;
    const int nb = (N + SCAN_ELEMS - 1) / SCAN_ELEMS;  // scan blocks (49 for N=100000)

    // ---- CSR build ----
    hipMemsetAsync(deg, 0, (size_t)N * sizeof(int), stream);
    k_deg<<<(EP + BS - 1) / BS, BS, 0, stream>>>(edst, E, N, deg);
    k_scan_a<<<nb, SCAN_T, 0, stream>>>(deg, rowstart, bsum, N);
    k_scan_b<<<1, 1024, 0, stream>>>(bsum, nb);
    k_scan_c<<<(N + BS - 1) / BS, BS, 0, stream>>>(rowstart, bsum, N);
    hipMemsetAsync(deg, 0, (size_t)N * sizeof(int), stream);   // reuse as cursor
    k_scatter<<<(EP + BS - 1) / BS, BS, 0, stream>>>(esrc, edst, E, N, rowstart, deg, csr_src);

    // ---- conv1 (one-hot factorized gather) ----
    k_node_att1<<<(N * HEADS + BS - 1) / BS, BS, 0, stream>>>(x, W1, as1, ad1, asrc_b, adst_b, N);
    k_gather1<<<N, DCH, 0, stream>>>(rowstart, csr_src, x, W1, asrc_b, adst_b, b1, bufA, N);

    // ---- conv3 ----
    k_gemm128<<<N, DCH, 0, stream>>>(bufA, W3, bufB, N);
    k_node_att3<<<(N * HEADS + BS - 1) / BS, BS, 0, stream>>>(bufB, as3, ad3, asrc_b, adst_b, N);
    k_gather3<<<N, DCH, 0, stream>>>(rowstart, csr_src, bufB, asrc_b, adst_b, b3, bufA, N);

    // ---- pool + classifier ----
    k_bounds<<<(N + 1 + BS - 1) / BS, BS, 0, stream>>>(batch, gstart, N, G);
    k_pool_final<<<G, DCH, 0, stream>>>(bufA, gstart, lw, lb, out, G);
}

// Round 3
// 540.753 us; speedup vs baseline: 4.0030x; 1.7588x over previous
//
#include <hip/hip_runtime.h>

#define HEADS 4
#define HID 32
#define DCH 128            // HEADS*HID
#define OUTC 10
#define NSLOPE 0.2f

#define SCAN_T 256
#define SCAN_PT 8
#define SCAN_ELEMS (SCAN_T * SCAN_PT)   // 2048 elements per scan block

#define GEMM_ROWS 32
#define POOL_BLOCKS 1024

// ---- per-node attention logits (conv1: W1 row gathered by class id)
__global__ void k_node_att1(const int* __restrict__ x, const float* __restrict__ W,
                            const float* __restrict__ att_src, const float* __restrict__ att_dst,
                            float* __restrict__ asrc, float* __restrict__ adst, int N) {
    int gid = blockIdx.x * blockDim.x + threadIdx.x;
    if (gid >= N * HEADS) return;
    int n = gid >> 2, h = gid & 3;
    const float* w  = W + (size_t)x[n] * DCH + h * HID;
    const float* as = att_src + h * HID;
    const float* ad = att_dst + h * HID;
    float s1 = 0.f, s2 = 0.f;
#pragma unroll
    for (int c = 0; c < HID; c++) { float wv = w[c]; s1 = fmaf(wv, as[c], s1); s2 = fmaf(wv, ad[c], s2); }
    asrc[gid] = s1; adst[gid] = s2;
}

// ---- conv3 variant: feature rows from dense hp [N,128]
__global__ void k_node_att3(const float* __restrict__ hp,
                            const float* __restrict__ att_src, const float* __restrict__ att_dst,
                            float* __restrict__ asrc, float* __restrict__ adst, int N) {
    int gid = blockIdx.x * blockDim.x + threadIdx.x;
    if (gid >= N * HEADS) return;
    int n = gid >> 2, h = gid & 3;
    const float* w  = hp + (size_t)n * DCH + h * HID;
    const float* as = att_src + h * HID;
    const float* ad = att_dst + h * HID;
    float s1 = 0.f, s2 = 0.f;
#pragma unroll
    for (int c = 0; c < HID; c++) { float wv = w[c]; s1 = fmaf(wv, as[c], s1); s2 = fmaf(wv, ad[c], s2); }
    asrc[gid] = s1; adst[gid] = s2;
}

// ================= CSR build (dst-major) =================
__global__ void k_deg(const int* __restrict__ edst, int E, int N, int* __restrict__ deg) {
    int e = blockIdx.x * blockDim.x + threadIdx.x;
    int EP = E + N;
    if (e >= EP) return;
    int d = (e < E) ? edst[e] : (e - E);     // self-loops appended
    atomicAdd(&deg[d], 1);
}

__global__ void k_scan_a(const int* __restrict__ deg, int* __restrict__ rowstart,
                         int* __restrict__ bsum, int N) {
    __shared__ int sh[SCAN_T];
    int base = blockIdx.x * SCAN_ELEMS;
    int t = threadIdx.x;
    int v[SCAN_PT];
    int s = 0;
#pragma unroll
    for (int i = 0; i < SCAN_PT; i++) {
        int idx = base + t * SCAN_PT + i;
        int dv = (idx < N) ? deg[idx] : 0;
        s += dv; v[i] = s;
    }
    sh[t] = s;
    __syncthreads();
    for (int off = 1; off < SCAN_T; off <<= 1) {
        int add = (t >= off) ? sh[t - off] : 0;
        __syncthreads();
        sh[t] += add;
        __syncthreads();
    }
    int excl = (t > 0) ? sh[t - 1] : 0;
#pragma unroll
    for (int i = 0; i < SCAN_PT; i++) {
        int idx = base + t * SCAN_PT + i;
        if (idx < N) rowstart[idx + 1] = v[i] + excl;
    }
    if (t == SCAN_T - 1) bsum[blockIdx.x] = sh[t];
}

__global__ void k_scan_b(int* __restrict__ bsum, int nb) {
    __shared__ int sh[1024];
    int t = threadIdx.x;
    sh[t] = (t < nb) ? bsum[t] : 0;
    __syncthreads();
    for (int off = 1; off < 1024; off <<= 1) {
        int add = (t >= off) ? sh[t - off] : 0;
        __syncthreads();
        sh[t] += add;
        __syncthreads();
    }
    if (t < nb) bsum[t] = (t > 0) ? sh[t - 1] : 0;
}

__global__ void k_scan_c(int* __restrict__ rowstart, const int* __restrict__ boff, int N) {
    int i = blockIdx.x * blockDim.x + threadIdx.x;
    if (i >= N) return;
    rowstart[i + 1] += boff[i / SCAN_ELEMS];
    if (i == 0) rowstart[0] = 0;
}

__global__ void k_scatter(const int* __restrict__ esrc, const int* __restrict__ edst,
                          int E, int N, const int* __restrict__ rowstart,
                          int* __restrict__ cursor, int* __restrict__ csr_src) {
    int e = blockIdx.x * blockDim.x + threadIdx.x;
    int EP = E + N;
    if (e >= EP) return;
    int s, d;
    if (e < E) { s = esrc[e]; d = edst[e]; } else { s = e - E; d = s; }
    int pos = rowstart[d] + atomicAdd(&cursor[d], 1);
    csr_src[pos] = s;
}

// ================= conv1 gather (one-hot factorized) =================
__global__ __launch_bounds__(128) void k_gather1(
        const int* __restrict__ rowstart, const int* __restrict__ csr_src,
        const int* __restrict__ x, const float* __restrict__ W1,
        const float* __restrict__ asrc, const float* __restrict__ adst,
        const float* __restrict__ bias, float* __restrict__ outh, int N) {
    __shared__ float lds[HEADS][HID + 1];
    int d = blockIdx.x;
    int c = threadIdx.x;
    int h = c >> 5, k = c & 31;
    float adst_h = adst[d * HEADS + h];
    int p0 = rowstart[d], p1 = rowstart[d + 1];
    float acc = 0.f;
    for (int p = p0; p < p1; p++) {
        int s = csr_src[p];
        float ev = asrc[s * HEADS + h] + adst_h;
        ev = ev >= 0.f ? ev : NSLOPE * ev;
        float ex = __expf(ev);
        if (x[s] == k) acc += ex;
    }
    lds[h][k] = acc;
    __syncthreads();
    float denom = 0.f, dot = 0.f;
#pragma unroll
    for (int kk = 0; kk < HID; kk++) {
        float a = lds[h][kk];
        denom += a;
        dot = fmaf(a, W1[kk * DCH + c], dot);
    }
    float v = dot / denom + bias[c];
    outh[(size_t)d * DCH + c] = v > 0.f ? v : 0.f;
}

// ================= conv3 gather =================
__global__ __launch_bounds__(128) void k_gather3(
        const int* __restrict__ rowstart, const int* __restrict__ csr_src,
        const float* __restrict__ hp, const float* __restrict__ asrc,
        const float* __restrict__ adst, const float* __restrict__ bias,
        float* __restrict__ outh, int N) {
    int d = blockIdx.x;
    int c = threadIdx.x;
    int h = c >> 5;
    float adst_h = adst[d * HEADS + h];
    int p0 = rowstart[d], p1 = rowstart[d + 1];
    float acc = 0.f, den = 0.f;
    for (int p = p0; p < p1; p++) {
        int s = csr_src[p];
        float ev = asrc[s * HEADS + h] + adst_h;
        ev = ev >= 0.f ? ev : NSLOPE * ev;
        float ex = __expf(ev);
        den += ex;
        acc = fmaf(ex, hp[(size_t)s * DCH + c], acc);
    }
    outh[(size_t)d * DCH + c] = acc / den + bias[c];
}

// ---- hp3 = h1 @ W3, 32 rows per block: W3 traffic amortized 32x
__global__ __launch_bounds__(128) void k_gemm_tiled(
        const float* __restrict__ A, const float* __restrict__ W,
        float* __restrict__ C, int N) {
    __shared__ float sh[GEMM_ROWS][DCH];
    int r0 = blockIdx.x * GEMM_ROWS;
    int t = threadIdx.x;
#pragma unroll
    for (int i = 0; i < GEMM_ROWS; i++) {
        int idx = i * DCH + t;               // coalesced: 128 consecutive per row
        int r = idx >> 7, k = idx & 127;
        int row = r0 + r;
        sh[r][k] = (row < N) ? A[(size_t)row * DCH + k] : 0.f;
    }
    __syncthreads();
    float acc[GEMM_ROWS];
#pragma unroll
    for (int r = 0; r < GEMM_ROWS; r++) acc[r] = 0.f;
    for (int k = 0; k < DCH; k++) {
        float w = W[k * DCH + t];
#pragma unroll
        for (int r = 0; r < GEMM_ROWS; r++) acc[r] = fmaf(sh[r][k], w, acc[r]);
    }
#pragma unroll
    for (int r = 0; r < GEMM_ROWS; r++) {
        int row = r0 + r;
        if (row < N) C[(size_t)row * DCH + t] = acc[r];
    }
}

// ---- graph boundaries from sorted batch
__global__ void k_bounds(const int* __restrict__ batch, int* __restrict__ gstart, int N, int G) {
    int n = blockIdx.x * blockDim.x + threadIdx.x;
    if (n > N) return;
    if (n == 0) {
        int b0 = batch[0];
        for (int g = 0; g <= b0; g++) gstart[g] = 0;
        return;
    }
    if (n == N) {
        int bl = batch[N - 1];
        for (int g = bl + 1; g <= G; g++) gstart[g] = N;
        return;
    }
    int b = batch[n], bp = batch[n - 1];
    for (int g = bp + 1; g <= b; g++) gstart[g] = n;
}

// ---- parallel mean-pool: slab of rows per block, flush at graph boundary
__global__ __launch_bounds__(128) void k_pool_partial(
        const float* __restrict__ h, const int* __restrict__ batch,
        float* __restrict__ pool, int N, int R) {
    int c = threadIdx.x;
    int n0 = blockIdx.x * R;
    if (n0 >= N) return;
    int n1 = n0 + R; if (n1 > N) n1 = N;
    float acc = 0.f;
    int curg = batch[n0];
    for (int n = n0; n < n1; n++) {
        int g = batch[n];                     // broadcast (all lanes same addr)
        if (g != curg) {
            atomicAdd(&pool[(size_t)curg * DCH + c], acc);
            acc = 0.f; curg = g;
        }
        acc += h[(size_t)n * DCH + c];
    }
    atomicAdd(&pool[(size_t)curg * DCH + c], acc);
}

// ---- divide by count + classifier
__global__ __launch_bounds__(128) void k_final(
        const float* __restrict__ pool, const int* __restrict__ gstart,
        const float* __restrict__ lw, const float* __restrict__ lb,
        float* __restrict__ out, int G) {
    __shared__ float pooled[DCH];
    int g = blockIdx.x, c = threadIdx.x;
    float cnt = (float)(gstart[g + 1] - gstart[g]);
    pooled[c] = pool[(size_t)g * DCH + c] / fmaxf(cnt, 1.f);
    __syncthreads();
    if (c < OUTC) {
        float acc = lb[c];
#pragma unroll 8
        for (int k = 0; k < DCH; k++) acc = fmaf(pooled[k], lw[k * OUTC + c], acc);
        out[g * OUTC + c] = acc;
    }
}

extern "C" void kernel_launch(void* const* d_in, const int* in_sizes, int n_in,
                              void* d_out, int out_size, void* d_ws, size_t ws_size,
                              hipStream_t stream) {
    const int*   x    = (const int*)d_in[0];
    const int*   eidx = (const int*)d_in[1];
    const int*   batch= (const int*)d_in[2];
    const float* W1   = (const float*)d_in[3];
    const float* as1  = (const float*)d_in[4];
    const float* ad1  = (const float*)d_in[5];
    const float* b1   = (const float*)d_in[6];
    const float* W3   = (const float*)d_in[7];
    const float* as3  = (const float*)d_in[8];
    const float* ad3  = (const float*)d_in[9];
    const float* b3   = (const float*)d_in[10];
    const float* lw   = (const float*)d_in[11];
    const float* lb   = (const float*)d_in[12];
    float* out = (float*)d_out;

    const int N  = in_sizes[0];
    const int E  = in_sizes[1] / 2;
    const int G  = out_size / OUTC;
    const int EP = E + N;
    const int* esrc = eidx;
    const int* edst = eidx + E;

    // ---- workspace layout ----
    float* bufA    = (float*)d_ws;                     // [N,128] h1, later out3
    float* bufB    = bufA + (size_t)N * DCH;           // [N,128] hproj3
    float* asrc_b  = bufB + (size_t)N * DCH;           // [N,4]
    float* adst_b  = asrc_b + (size_t)N * HEADS;       // [N,4]
    int*   deg     = (int*)(adst_b + (size_t)N * HEADS); // [N] degree, then cursor
    int*   rowstart= deg + N;                          // [N+1]
    int*   bsum    = rowstart + (N + 1);               // [<=1024]
    int*   csr_src = bsum + 1024;                      // [EP]
    int*   gstart  = csr_src + EP;                     // [G+1]
    float* pool    = (float*)(gstart + (G + 1));       // [G,128]

    const int BS = 256;
    const int nb = (N + SCAN_ELEMS - 1) / SCAN_ELEMS;

    // ---- CSR build ----
    hipMemsetAsync(deg, 0, (size_t)N * sizeof(int), stream);
    k_deg<<<(EP + BS - 1) / BS, BS, 0, stream>>>(edst, E, N, deg);
    k_scan_a<<<nb, SCAN_T, 0, stream>>>(deg, rowstart, bsum, N);
    k_scan_b<<<1, 1024, 0, stream>>>(bsum, nb);
    k_scan_c<<<(N + BS - 1) / BS, BS, 0, stream>>>(rowstart, bsum, N);
    hipMemsetAsync(deg, 0, (size_t)N * sizeof(int), stream);   // reuse as cursor
    k_scatter<<<(EP + BS - 1) / BS, BS, 0, stream>>>(esrc, edst, E, N, rowstart, deg, csr_src);

    // ---- conv1 ----
    k_node_att1<<<(N * HEADS + BS - 1) / BS, BS, 0, stream>>>(x, W1, as1, ad1, asrc_b, adst_b, N);
    k_gather1<<<N, DCH, 0, stream>>>(rowstart, csr_src, x, W1, asrc_b, adst_b, b1, bufA, N);

    // ---- conv3 ----
    k_gemm_tiled<<<(N + GEMM_ROWS - 1) / GEMM_ROWS, DCH, 0, stream>>>(bufA, W3, bufB, N);
    k_node_att3<<<(N * HEADS + BS - 1) / BS, BS, 0, stream>>>(bufB, as3, ad3, asrc_b, adst_b, N);
    k_gather3<<<N, DCH, 0, stream>>>(rowstart, csr_src, bufB, asrc_b, adst_b, b3, bufA, N);

    // ---- pool + classifier ----
    k_bounds<<<(N + 1 + BS - 1) / BS, BS, 0, stream>>>(batch, gstart, N, G);
    hipMemsetAsync(pool, 0, (size_t)G * DCH * sizeof(float), stream);
    {
        int R = (N + POOL_BLOCKS - 1) / POOL_BLOCKS;
        k_pool_partial<<<POOL_BLOCKS, DCH, 0, stream>>>(bufA, batch, pool, N, R);
    }
    k_final<<<G, DCH, 0, stream>>>(pool, gstart, lw, lb, out, G);
}

// Round 4
// 407.154 us; speedup vs baseline: 5.3165x; 1.3281x over previous
//
#include <hip/hip_runtime.h>

#define HEADS 4
#define HID 32
#define DCH 128            // HEADS*HID
#define OUTC 10
#define NSLOPE 0.2f

#define SCAN_T 256
#define SCAN_PT 8
#define SCAN_ELEMS (SCAN_T * SCAN_PT)   // 2048 elements per scan block

#define GR 64              // gemm rows per block
#define POOL_BLOCKS 1024
#define CHUNK 32           // edges staged per gather chunk

// ---- per-node attention logits (conv1: W1 row gathered by class id)
__global__ void k_node_att1(const int* __restrict__ x, const float* __restrict__ W,
                            const float* __restrict__ att_src, const float* __restrict__ att_dst,
                            float* __restrict__ asrc, float* __restrict__ adst, int N) {
    int gid = blockIdx.x * blockDim.x + threadIdx.x;
    if (gid >= N * HEADS) return;
    int n = gid >> 2, h = gid & 3;
    const float* w  = W + (size_t)x[n] * DCH + h * HID;
    const float* as = att_src + h * HID;
    const float* ad = att_dst + h * HID;
    float s1 = 0.f, s2 = 0.f;
#pragma unroll
    for (int c = 0; c < HID; c++) { float wv = w[c]; s1 = fmaf(wv, as[c], s1); s2 = fmaf(wv, ad[c], s2); }
    asrc[gid] = s1; adst[gid] = s2;
}

// ---- conv3 variant: feature rows from dense hp [N,128]
__global__ void k_node_att3(const float* __restrict__ hp,
                            const float* __restrict__ att_src, const float* __restrict__ att_dst,
                            float* __restrict__ asrc, float* __restrict__ adst, int N) {
    int gid = blockIdx.x * blockDim.x + threadIdx.x;
    if (gid >= N * HEADS) return;
    int n = gid >> 2, h = gid & 3;
    const float* w  = hp + (size_t)n * DCH + h * HID;
    const float* as = att_src + h * HID;
    const float* ad = att_dst + h * HID;
    float s1 = 0.f, s2 = 0.f;
#pragma unroll
    for (int c = 0; c < HID; c++) { float wv = w[c]; s1 = fmaf(wv, as[c], s1); s2 = fmaf(wv, ad[c], s2); }
    asrc[gid] = s1; adst[gid] = s2;
}

// ================= CSR build (dst-major) =================
__global__ void k_deg(const int* __restrict__ edst, int E, int N, int* __restrict__ deg) {
    int e = blockIdx.x * blockDim.x + threadIdx.x;
    int EP = E + N;
    if (e >= EP) return;
    int d = (e < E) ? edst[e] : (e - E);     // self-loops appended
    atomicAdd(&deg[d], 1);
}

__global__ void k_scan_a(const int* __restrict__ deg, int* __restrict__ rowstart,
                         int* __restrict__ bsum, int N) {
    __shared__ int sh[SCAN_T];
    int base = blockIdx.x * SCAN_ELEMS;
    int t = threadIdx.x;
    int v[SCAN_PT];
    int s = 0;
#pragma unroll
    for (int i = 0; i < SCAN_PT; i++) {
        int idx = base + t * SCAN_PT + i;
        int dv = (idx < N) ? deg[idx] : 0;
        s += dv; v[i] = s;
    }
    sh[t] = s;
    __syncthreads();
    for (int off = 1; off < SCAN_T; off <<= 1) {
        int add = (t >= off) ? sh[t - off] : 0;
        __syncthreads();
        sh[t] += add;
        __syncthreads();
    }
    int excl = (t > 0) ? sh[t - 1] : 0;
#pragma unroll
    for (int i = 0; i < SCAN_PT; i++) {
        int idx = base + t * SCAN_PT + i;
        if (idx < N) rowstart[idx + 1] = v[i] + excl;
    }
    if (t == SCAN_T - 1) bsum[blockIdx.x] = sh[t];
}

__global__ void k_scan_b(int* __restrict__ bsum, int nb) {
    __shared__ int sh[1024];
    int t = threadIdx.x;
    sh[t] = (t < nb) ? bsum[t] : 0;
    __syncthreads();
    for (int off = 1; off < 1024; off <<= 1) {
        int add = (t >= off) ? sh[t - off] : 0;
        __syncthreads();
        sh[t] += add;
        __syncthreads();
    }
    if (t < nb) bsum[t] = (t > 0) ? sh[t - 1] : 0;
}

__global__ void k_scan_c(int* __restrict__ rowstart, const int* __restrict__ boff, int N) {
    int i = blockIdx.x * blockDim.x + threadIdx.x;
    if (i >= N) return;
    rowstart[i + 1] += boff[i / SCAN_ELEMS];
    if (i == 0) rowstart[0] = 0;
}

__global__ void k_scatter(const int* __restrict__ esrc, const int* __restrict__ edst,
                          int E, int N, const int* __restrict__ rowstart,
                          int* __restrict__ cursor, int* __restrict__ csr_src) {
    int e = blockIdx.x * blockDim.x + threadIdx.x;
    int EP = E + N;
    if (e >= EP) return;
    int s, d;
    if (e < E) { s = esrc[e]; d = edst[e]; } else { s = e - E; d = s; }
    int pos = rowstart[d] + atomicAdd(&cursor[d], 1);
    csr_src[pos] = s;
}

// ================= conv1 gather (one-hot factorized, chunked exp) =================
__global__ __launch_bounds__(128) void k_gather1(
        const int* __restrict__ rowstart, const int* __restrict__ csr_src,
        const int* __restrict__ x, const float* __restrict__ W1,
        const float* __restrict__ asrc, const float* __restrict__ adst,
        const float* __restrict__ bias, float* __restrict__ outh, int N) {
    __shared__ int   s_sh[CHUNK];
    __shared__ int   x_sh[CHUNK];
    __shared__ float ex_sh[CHUNK][HEADS];
    __shared__ float cls[HEADS][HID + 1];
    int d = blockIdx.x;
    int c = threadIdx.x;
    int h = c >> 5, k = c & 31;
    int i4 = c >> 2, h4 = c & 3;
    int p0 = rowstart[d], p1 = rowstart[d + 1];
    float acc = 0.f;
    for (int base = p0; base < p1; base += CHUNK) {
        int m = p1 - base; if (m > CHUNK) m = CHUNK;
        __syncthreads();                          // previous chunk consumed
        if (c < m) { int s = csr_src[base + c]; s_sh[c] = s; x_sh[c] = x[s]; }
        __syncthreads();
        if (i4 < m) {                             // 4 exps per edge, computed once
            int s = s_sh[i4];
            float ev = asrc[s * HEADS + h4] + adst[d * HEADS + h4];
            ev = ev >= 0.f ? ev : NSLOPE * ev;
            ex_sh[i4][h4] = __expf(ev);
        }
        __syncthreads();
        for (int i = 0; i < m; i++)
            if (x_sh[i] == k) acc += ex_sh[i][h];
    }
    cls[h][k] = acc;
    __syncthreads();
    float denom = 0.f, dot = 0.f;
#pragma unroll
    for (int kk = 0; kk < HID; kk++) {
        float a = cls[h][kk];
        denom += a;
        dot = fmaf(a, W1[kk * DCH + c], dot);
    }
    float v = dot / denom + bias[c];
    outh[(size_t)d * DCH + c] = v > 0.f ? v : 0.f;
}

// ================= conv3 gather (chunked exp) =================
__global__ __launch_bounds__(128) void k_gather3(
        const int* __restrict__ rowstart, const int* __restrict__ csr_src,
        const float* __restrict__ hp, const float* __restrict__ asrc,
        const float* __restrict__ adst, const float* __restrict__ bias,
        float* __restrict__ outh, int N) {
    __shared__ int   s_sh[CHUNK];
    __shared__ float ex_sh[CHUNK][HEADS];
    int d = blockIdx.x;
    int c = threadIdx.x;
    int h = c >> 5;
    int i4 = c >> 2, h4 = c & 3;
    int p0 = rowstart[d], p1 = rowstart[d + 1];
    float acc = 0.f, den = 0.f;
    for (int base = p0; base < p1; base += CHUNK) {
        int m = p1 - base; if (m > CHUNK) m = CHUNK;
        __syncthreads();
        if (c < m) s_sh[c] = csr_src[base + c];
        __syncthreads();
        if (i4 < m) {
            int s = s_sh[i4];
            float ev = asrc[s * HEADS + h4] + adst[d * HEADS + h4];
            ev = ev >= 0.f ? ev : NSLOPE * ev;
            ex_sh[i4][h4] = __expf(ev);
        }
        __syncthreads();
        for (int i = 0; i < m; i++) {
            float ex = ex_sh[i][h];
            den += ex;
            acc = fmaf(ex, hp[(size_t)s_sh[i] * DCH + c], acc);
        }
    }
    outh[(size_t)d * DCH + c] = acc / den + bias[c];
}

// ---- hp3 = h1 @ W3, register-blocked 8x4 per thread (64x128 tile / block)
__global__ __launch_bounds__(256) void k_gemm_rb(
        const float* __restrict__ A, const float* __restrict__ W,
        float* __restrict__ C, int N) {
    __shared__ float sh[GR][DCH];                 // 32 KB
    int r0 = blockIdx.x * GR;
    int t = threadIdx.x;
#pragma unroll
    for (int i = 0; i < 8; i++) {
        int idx = i * 256 + t;                    // 2048 float4 in tile
        int r = idx >> 5, k4 = idx & 31;
        int row = r0 + r;
        float4 v = make_float4(0.f, 0.f, 0.f, 0.f);
        if (row < N) v = ((const float4*)A)[(size_t)row * (DCH / 4) + k4];
        *(float4*)&sh[r][k4 * 4] = v;
    }
    __syncthreads();
    int ct = t & 31, rt = t >> 5;                 // 32 col-threads x 8 row-threads
    float acc[8][4];
#pragma unroll
    for (int r = 0; r < 8; r++)
#pragma unroll
        for (int j = 0; j < 4; j++) acc[r][j] = 0.f;
    for (int k = 0; k < DCH; k += 4) {
        float wreg[4][4];
#pragma unroll
        for (int kk = 0; kk < 4; kk++) {
            float4 wv = *(const float4*)&W[(size_t)(k + kk) * DCH + ct * 4];
            wreg[kk][0] = wv.x; wreg[kk][1] = wv.y; wreg[kk][2] = wv.z; wreg[kk][3] = wv.w;
        }
#pragma unroll
        for (int r = 0; r < 8; r++) {
            float4 av = *(const float4*)&sh[rt * 8 + r][k];
            float areg[4] = {av.x, av.y, av.z, av.w};
#pragma unroll
            for (int kk = 0; kk < 4; kk++)
#pragma unroll
                for (int j = 0; j < 4; j++)
                    acc[r][j] = fmaf(areg[kk], wreg[kk][j], acc[r][j]);
        }
    }
#pragma unroll
    for (int r = 0; r < 8; r++) {
        int row = r0 + rt * 8 + r;
        if (row < N)
            *(float4*)&C[(size_t)row * DCH + ct * 4] =
                make_float4(acc[r][0], acc[r][1], acc[r][2], acc[r][3]);
    }
}

// ---- graph boundaries from sorted batch
__global__ void k_bounds(const int* __restrict__ batch, int* __restrict__ gstart, int N, int G) {
    int n = blockIdx.x * blockDim.x + threadIdx.x;
    if (n > N) return;
    if (n == 0) {
        int b0 = batch[0];
        for (int g = 0; g <= b0; g++) gstart[g] = 0;
        return;
    }
    if (n == N) {
        int bl = batch[N - 1];
        for (int g = bl + 1; g <= G; g++) gstart[g] = N;
        return;
    }
    int b = batch[n], bp = batch[n - 1];
    for (int g = bp + 1; g <= b; g++) gstart[g] = n;
}

// ---- parallel mean-pool: slab of rows per block, flush at graph boundary
__global__ __launch_bounds__(128) void k_pool_partial(
        const float* __restrict__ h, const int* __restrict__ batch,
        float* __restrict__ pool, int N, int R) {
    int c = threadIdx.x;
    int n0 = blockIdx.x * R;
    if (n0 >= N) return;
    int n1 = n0 + R; if (n1 > N) n1 = N;
    float acc = 0.f;
    int curg = batch[n0];
    for (int n = n0; n < n1; n++) {
        int g = batch[n];
        if (g != curg) {
            atomicAdd(&pool[(size_t)curg * DCH + c], acc);
            acc = 0.f; curg = g;
        }
        acc += h[(size_t)n * DCH + c];
    }
    atomicAdd(&pool[(size_t)curg * DCH + c], acc);
}

// ---- divide by count + classifier
__global__ __launch_bounds__(128) void k_final(
        const float* __restrict__ pool, const int* __restrict__ gstart,
        const float* __restrict__ lw, const float* __restrict__ lb,
        float* __restrict__ out, int G) {
    __shared__ float pooled[DCH];
    int g = blockIdx.x, c = threadIdx.x;
    float cnt = (float)(gstart[g + 1] - gstart[g]);
    pooled[c] = pool[(size_t)g * DCH + c] / fmaxf(cnt, 1.f);
    __syncthreads();
    if (c < OUTC) {
        float acc = lb[c];
#pragma unroll 8
        for (int k = 0; k < DCH; k++) acc = fmaf(pooled[k], lw[k * OUTC + c], acc);
        out[g * OUTC + c] = acc;
    }
}

extern "C" void kernel_launch(void* const* d_in, const int* in_sizes, int n_in,
                              void* d_out, int out_size, void* d_ws, size_t ws_size,
                              hipStream_t stream) {
    const int*   x    = (const int*)d_in[0];
    const int*   eidx = (const int*)d_in[1];
    const int*   batch= (const int*)d_in[2];
    const float* W1   = (const float*)d_in[3];
    const float* as1  = (const float*)d_in[4];
    const float* ad1  = (const float*)d_in[5];
    const float* b1   = (const float*)d_in[6];
    const float* W3   = (const float*)d_in[7];
    const float* as3  = (const float*)d_in[8];
    const float* ad3  = (const float*)d_in[9];
    const float* b3   = (const float*)d_in[10];
    const float* lw   = (const float*)d_in[11];
    const float* lb   = (const float*)d_in[12];
    float* out = (float*)d_out;

    const int N  = in_sizes[0];
    const int E  = in_sizes[1] / 2;
    const int G  = out_size / OUTC;
    const int EP = E + N;
    const int* esrc = eidx;
    const int* edst = eidx + E;

    // ---- workspace layout ----
    float* bufA    = (float*)d_ws;                     // [N,128] h1, later out3
    float* bufB    = bufA + (size_t)N * DCH;           // [N,128] hproj3
    float* asrc_b  = bufB + (size_t)N * DCH;           // [N,4]
    float* adst_b  = asrc_b + (size_t)N * HEADS;       // [N,4]
    int*   deg     = (int*)(adst_b + (size_t)N * HEADS); // [N] degree, then cursor
    int*   rowstart= deg + N;                          // [N+1]
    int*   bsum    = rowstart + (N + 1);               // [<=1024]
    int*   csr_src = bsum + 1024;                      // [EP]
    int*   gstart  = csr_src + EP;                     // [G+1]
    float* pool    = (float*)(gstart + (G + 1));       // [G,128]

    const int BS = 256;
    const int nb = (N + SCAN_ELEMS - 1) / SCAN_ELEMS;

    // ---- CSR build ----
    hipMemsetAsync(deg, 0, (size_t)N * sizeof(int), stream);
    k_deg<<<(EP + BS - 1) / BS, BS, 0, stream>>>(edst, E, N, deg);
    k_scan_a<<<nb, SCAN_T, 0, stream>>>(deg, rowstart, bsum, N);
    k_scan_b<<<1, 1024, 0, stream>>>(bsum, nb);
    k_scan_c<<<(N + BS - 1) / BS, BS, 0, stream>>>(rowstart, bsum, N);
    hipMemsetAsync(deg, 0, (size_t)N * sizeof(int), stream);   // reuse as cursor
    k_scatter<<<(EP + BS - 1) / BS, BS, 0, stream>>>(esrc, edst, E, N, rowstart, deg, csr_src);

    // ---- conv1 ----
    k_node_att1<<<(N * HEADS + BS - 1) / BS, BS, 0, stream>>>(x, W1, as1, ad1, asrc_b, adst_b, N);
    k_gather1<<<N, DCH, 0, stream>>>(rowstart, csr_src, x, W1, asrc_b, adst_b, b1, bufA, N);

    // ---- conv3 ----
    k_gemm_rb<<<(N + GR - 1) / GR, 256, 0, stream>>>(bufA, W3, bufB, N);
    k_node_att3<<<(N * HEADS + BS - 1) / BS, BS, 0, stream>>>(bufB, as3, ad3, asrc_b, adst_b, N);
    k_gather3<<<N, DCH, 0, stream>>>(rowstart, csr_src, bufB, asrc_b, adst_b, b3, bufA, N);

    // ---- pool + classifier ----
    k_bounds<<<(N + 1 + BS - 1) / BS, BS, 0, stream>>>(batch, gstart, N, G);
    hipMemsetAsync(pool, 0, (size_t)G * DCH * sizeof(float), stream);
    {
        int R = (N + POOL_BLOCKS - 1) / POOL_BLOCKS;
        k_pool_partial<<<POOL_BLOCKS, DCH, 0, stream>>>(bufA, batch, pool, N, R);
    }
    k_final<<<G, DCH, 0, stream>>>(pool, gstart, lw, lb, out, G);
}

// Round 5
// 384.767 us; speedup vs baseline: 5.6258x; 1.0582x over previous
//
#include <hip/hip_runtime.h>
#include <hip/hip_fp16.h>

#define HEADS 4
#define HID 32
#define DCH 128            // HEADS*HID
#define OUTC 10
#define NSLOPE 0.2f

#define SCAN_T 256
#define SCAN_PT 8
#define SCAN_ELEMS (SCAN_T * SCAN_PT)   // 2048 elements per scan block

#define GR 64              // gemm rows per block
#define POOL_BLOCKS 1024
#define CHUNK 32           // edges staged per gather chunk

// ---- per-node attention logits (conv1: W1 row gathered by class id)
__global__ void k_node_att1(const int* __restrict__ x, const float* __restrict__ W,
                            const float* __restrict__ att_src, const float* __restrict__ att_dst,
                            float* __restrict__ asrc, float* __restrict__ adst, int N) {
    int gid = blockIdx.x * blockDim.x + threadIdx.x;
    if (gid >= N * HEADS) return;
    int n = gid >> 2, h = gid & 3;
    const float* w  = W + (size_t)x[n] * DCH + h * HID;
    const float* as = att_src + h * HID;
    const float* ad = att_dst + h * HID;
    float s1 = 0.f, s2 = 0.f;
#pragma unroll
    for (int c = 0; c < HID; c++) { float wv = w[c]; s1 = fmaf(wv, as[c], s1); s2 = fmaf(wv, ad[c], s2); }
    asrc[gid] = s1; adst[gid] = s2;
}

// ---- conv3 variant: feature rows from fp16 hp [N,128]
__global__ void k_node_att3(const __half* __restrict__ hp,
                            const float* __restrict__ att_src, const float* __restrict__ att_dst,
                            float* __restrict__ asrc, float* __restrict__ adst, int N) {
    int gid = blockIdx.x * blockDim.x + threadIdx.x;
    if (gid >= N * HEADS) return;
    int n = gid >> 2, h = gid & 3;
    const __half2* w2 = (const __half2*)(hp + (size_t)n * DCH + h * HID);
    const float* as = att_src + h * HID;
    const float* ad = att_dst + h * HID;
    float s1 = 0.f, s2 = 0.f;
#pragma unroll
    for (int c2 = 0; c2 < HID / 2; c2++) {
        float2 f = __half22float2(w2[c2]);
        s1 = fmaf(f.x, as[c2 * 2], s1);     s2 = fmaf(f.x, ad[c2 * 2], s2);
        s1 = fmaf(f.y, as[c2 * 2 + 1], s1); s2 = fmaf(f.y, ad[c2 * 2 + 1], s2);
    }
    asrc[gid] = s1; adst[gid] = s2;
}

// ================= CSR build (dst-major) =================
__global__ void k_deg(const int* __restrict__ edst, int E, int N, int* __restrict__ deg) {
    int e = blockIdx.x * blockDim.x + threadIdx.x;
    int EP = E + N;
    if (e >= EP) return;
    int d = (e < E) ? edst[e] : (e - E);     // self-loops appended
    atomicAdd(&deg[d], 1);
}

__global__ void k_scan_a(const int* __restrict__ deg, int* __restrict__ rowstart,
                         int* __restrict__ bsum, int N) {
    __shared__ int sh[SCAN_T];
    int base = blockIdx.x * SCAN_ELEMS;
    int t = threadIdx.x;
    int v[SCAN_PT];
    int s = 0;
#pragma unroll
    for (int i = 0; i < SCAN_PT; i++) {
        int idx = base + t * SCAN_PT + i;
        int dv = (idx < N) ? deg[idx] : 0;
        s += dv; v[i] = s;
    }
    sh[t] = s;
    __syncthreads();
    for (int off = 1; off < SCAN_T; off <<= 1) {
        int add = (t >= off) ? sh[t - off] : 0;
        __syncthreads();
        sh[t] += add;
        __syncthreads();
    }
    int excl = (t > 0) ? sh[t - 1] : 0;
#pragma unroll
    for (int i = 0; i < SCAN_PT; i++) {
        int idx = base + t * SCAN_PT + i;
        if (idx < N) rowstart[idx + 1] = v[i] + excl;
    }
    if (t == SCAN_T - 1) bsum[blockIdx.x] = sh[t];
}

__global__ void k_scan_b(int* __restrict__ bsum, int nb) {
    __shared__ int sh[1024];
    int t = threadIdx.x;
    sh[t] = (t < nb) ? bsum[t] : 0;
    __syncthreads();
    for (int off = 1; off < 1024; off <<= 1) {
        int add = (t >= off) ? sh[t - off] : 0;
        __syncthreads();
        sh[t] += add;
        __syncthreads();
    }
    if (t < nb) bsum[t] = (t > 0) ? sh[t - 1] : 0;
}

__global__ void k_scan_c(int* __restrict__ rowstart, const int* __restrict__ boff, int N) {
    int i = blockIdx.x * blockDim.x + threadIdx.x;
    if (i >= N) return;
    rowstart[i + 1] += boff[i / SCAN_ELEMS];
    if (i == 0) rowstart[0] = 0;
}

__global__ void k_scatter(const int* __restrict__ esrc, const int* __restrict__ edst,
                          int E, int N, const int* __restrict__ rowstart,
                          int* __restrict__ cursor, int* __restrict__ csr_src) {
    int e = blockIdx.x * blockDim.x + threadIdx.x;
    int EP = E + N;
    if (e >= EP) return;
    int s, d;
    if (e < E) { s = esrc[e]; d = edst[e]; } else { s = e - E; d = s; }
    int pos = rowstart[d] + atomicAdd(&cursor[d], 1);
    csr_src[pos] = s;
}

// ================= conv1 gather (one-hot factorized, chunked exp) =================
__global__ __launch_bounds__(128) void k_gather1(
        const int* __restrict__ rowstart, const int* __restrict__ csr_src,
        const int* __restrict__ x, const float* __restrict__ W1,
        const float* __restrict__ asrc, const float* __restrict__ adst,
        const float* __restrict__ bias, float* __restrict__ outh, int N) {
    __shared__ int   s_sh[CHUNK];
    __shared__ int   x_sh[CHUNK];
    __shared__ float ex_sh[CHUNK][HEADS];
    __shared__ float cls[HEADS][HID + 1];
    int d = blockIdx.x;
    int c = threadIdx.x;
    int h = c >> 5, k = c & 31;
    int i4 = c >> 2, h4 = c & 3;
    int p0 = rowstart[d], p1 = rowstart[d + 1];
    float acc = 0.f;
    for (int base = p0; base < p1; base += CHUNK) {
        int m = p1 - base; if (m > CHUNK) m = CHUNK;
        __syncthreads();                          // previous chunk consumed
        if (c < m) { int s = csr_src[base + c]; s_sh[c] = s; x_sh[c] = x[s]; }
        __syncthreads();
        if (i4 < m) {                             // 4 exps per edge, computed once
            int s = s_sh[i4];
            float ev = asrc[s * HEADS + h4] + adst[d * HEADS + h4];
            ev = ev >= 0.f ? ev : NSLOPE * ev;
            ex_sh[i4][h4] = __expf(ev);
        }
        __syncthreads();
        for (int i = 0; i < m; i++)
            if (x_sh[i] == k) acc += ex_sh[i][h];
    }
    cls[h][k] = acc;
    __syncthreads();
    float denom = 0.f, dot = 0.f;
#pragma unroll
    for (int kk = 0; kk < HID; kk++) {
        float a = cls[h][kk];
        denom += a;
        dot = fmaf(a, W1[kk * DCH + c], dot);
    }
    float v = dot / denom + bias[c];
    outh[(size_t)d * DCH + c] = v > 0.f ? v : 0.f;
}

// ================= conv3 gather: 4 edge-groups x 32 lanes, fp16 rows =================
__global__ __launch_bounds__(128) void k_gather3(
        const int* __restrict__ rowstart, const int* __restrict__ csr_src,
        const __half* __restrict__ hp, const float* __restrict__ asrc,
        const float* __restrict__ adst, const float* __restrict__ bias,
        float* __restrict__ outh, int N) {
    __shared__ int   s_sh[CHUNK];
    __shared__ float ex_sh[CHUNK][HEADS];
    __shared__ float accP[4][DCH];
    __shared__ float denP[4][HEADS];
    int d = blockIdx.x;
    int c = threadIdx.x;
    int lane = c & 31, grp = c >> 5;         // lane covers channels 4*lane..4*lane+3
    int myh = lane >> 3;                      // head of those channels
    int i4 = c >> 2, h4 = c & 3;
    int p0 = rowstart[d], p1 = rowstart[d + 1];
    float a0 = 0.f, a1 = 0.f, a2 = 0.f, a3 = 0.f, den = 0.f;
    for (int base = p0; base < p1; base += CHUNK) {
        int m = p1 - base; if (m > CHUNK) m = CHUNK;
        __syncthreads();
        if (c < m) s_sh[c] = csr_src[base + c];
        __syncthreads();
        if (i4 < m) {
            int s = s_sh[i4];
            float ev = asrc[s * HEADS + h4] + adst[d * HEADS + h4];
            ev = ev >= 0.f ? ev : NSLOPE * ev;
            ex_sh[i4][h4] = __expf(ev);
        }
        __syncthreads();
        for (int i = grp; i < m; i += 4) {    // 4 edges in flight per block
            float ex = ex_sh[i][myh];
            den += ex;
            const uint2 raw = *(const uint2*)(hp + (size_t)s_sh[i] * DCH + lane * 4);
            __half2 h0 = *(const __half2*)&raw.x;
            __half2 h1 = *(const __half2*)&raw.y;
            float2 f0 = __half22float2(h0);
            float2 f1 = __half22float2(h1);
            a0 = fmaf(ex, f0.x, a0);
            a1 = fmaf(ex, f0.y, a1);
            a2 = fmaf(ex, f1.x, a2);
            a3 = fmaf(ex, f1.y, a3);
        }
    }
    accP[grp][lane * 4 + 0] = a0;
    accP[grp][lane * 4 + 1] = a1;
    accP[grp][lane * 4 + 2] = a2;
    accP[grp][lane * 4 + 3] = a3;
    if ((lane & 7) == 0) denP[grp][myh] = den;
    __syncthreads();
    int hh = c >> 5;
    float a = accP[0][c] + accP[1][c] + accP[2][c] + accP[3][c];
    float dn = denP[0][hh] + denP[1][hh] + denP[2][hh] + denP[3][hh];
    outh[(size_t)d * DCH + c] = a / dn + bias[c];
}

// ---- hp3 = h1 @ W3, register-blocked 8x4 per thread, fp16 output
__global__ __launch_bounds__(256) void k_gemm_rb(
        const float* __restrict__ A, const float* __restrict__ W,
        __half* __restrict__ C, int N) {
    __shared__ float sh[GR][DCH];                 // 32 KB
    int r0 = blockIdx.x * GR;
    int t = threadIdx.x;
#pragma unroll
    for (int i = 0; i < 8; i++) {
        int idx = i * 256 + t;                    // 2048 float4 in tile
        int r = idx >> 5, k4 = idx & 31;
        int row = r0 + r;
        float4 v = make_float4(0.f, 0.f, 0.f, 0.f);
        if (row < N) v = ((const float4*)A)[(size_t)row * (DCH / 4) + k4];
        *(float4*)&sh[r][k4 * 4] = v;
    }
    __syncthreads();
    int ct = t & 31, rt = t >> 5;                 // 32 col-threads x 8 row-threads
    float acc[8][4];
#pragma unroll
    for (int r = 0; r < 8; r++)
#pragma unroll
        for (int j = 0; j < 4; j++) acc[r][j] = 0.f;
    for (int k = 0; k < DCH; k += 4) {
        float wreg[4][4];
#pragma unroll
        for (int kk = 0; kk < 4; kk++) {
            float4 wv = *(const float4*)&W[(size_t)(k + kk) * DCH + ct * 4];
            wreg[kk][0] = wv.x; wreg[kk][1] = wv.y; wreg[kk][2] = wv.z; wreg[kk][3] = wv.w;
        }
#pragma unroll
        for (int r = 0; r < 8; r++) {
            float4 av = *(const float4*)&sh[rt * 8 + r][k];
            float areg[4] = {av.x, av.y, av.z, av.w};
#pragma unroll
            for (int kk = 0; kk < 4; kk++)
#pragma unroll
                for (int j = 0; j < 4; j++)
                    acc[r][j] = fmaf(areg[kk], wreg[kk][j], acc[r][j]);
        }
    }
#pragma unroll
    for (int r = 0; r < 8; r++) {
        int row = r0 + rt * 8 + r;
        if (row < N) {
            union { __half h[4]; uint2 u; } pk;
#pragma unroll
            for (int j = 0; j < 4; j++) pk.h[j] = __float2half(acc[r][j]);
            *(uint2*)&C[(size_t)row * DCH + ct * 4] = pk.u;
        }
    }
}

// ---- graph boundaries from sorted batch
__global__ void k_bounds(const int* __restrict__ batch, int* __restrict__ gstart, int N, int G) {
    int n = blockIdx.x * blockDim.x + threadIdx.x;
    if (n > N) return;
    if (n == 0) {
        int b0 = batch[0];
        for (int g = 0; g <= b0; g++) gstart[g] = 0;
        return;
    }
    if (n == N) {
        int bl = batch[N - 1];
        for (int g = bl + 1; g <= G; g++) gstart[g] = N;
        return;
    }
    int b = batch[n], bp = batch[n - 1];
    for (int g = bp + 1; g <= b; g++) gstart[g] = n;
}

// ---- parallel mean-pool: slab of rows per block, flush at graph boundary
__global__ __launch_bounds__(128) void k_pool_partial(
        const float* __restrict__ h, const int* __restrict__ batch,
        float* __restrict__ pool, int N, int R) {
    int c = threadIdx.x;
    int n0 = blockIdx.x * R;
    if (n0 >= N) return;
    int n1 = n0 + R; if (n1 > N) n1 = N;
    float acc = 0.f;
    int curg = batch[n0];
    for (int n = n0; n < n1; n++) {
        int g = batch[n];
        if (g != curg) {
            atomicAdd(&pool[(size_t)curg * DCH + c], acc);
            acc = 0.f; curg = g;
        }
        acc += h[(size_t)n * DCH + c];
    }
    atomicAdd(&pool[(size_t)curg * DCH + c], acc);
}

// ---- divide by count + classifier
__global__ __launch_bounds__(128) void k_final(
        const float* __restrict__ pool, const int* __restrict__ gstart,
        const float* __restrict__ lw, const float* __restrict__ lb,
        float* __restrict__ out, int G) {
    __shared__ float pooled[DCH];
    int g = blockIdx.x, c = threadIdx.x;
    float cnt = (float)(gstart[g + 1] - gstart[g]);
    pooled[c] = pool[(size_t)g * DCH + c] / fmaxf(cnt, 1.f);
    __syncthreads();
    if (c < OUTC) {
        float acc = lb[c];
#pragma unroll 8
        for (int k = 0; k < DCH; k++) acc = fmaf(pooled[k], lw[k * OUTC + c], acc);
        out[g * OUTC + c] = acc;
    }
}

extern "C" void kernel_launch(void* const* d_in, const int* in_sizes, int n_in,
                              void* d_out, int out_size, void* d_ws, size_t ws_size,
                              hipStream_t stream) {
    const int*   x    = (const int*)d_in[0];
    const int*   eidx = (const int*)d_in[1];
    const int*   batch= (const int*)d_in[2];
    const float* W1   = (const float*)d_in[3];
    const float* as1  = (const float*)d_in[4];
    const float* ad1  = (const float*)d_in[5];
    const float* b1   = (const float*)d_in[6];
    const float* W3   = (const float*)d_in[7];
    const float* as3  = (const float*)d_in[8];
    const float* ad3  = (const float*)d_in[9];
    const float* b3   = (const float*)d_in[10];
    const float* lw   = (const float*)d_in[11];
    const float* lb   = (const float*)d_in[12];
    float* out = (float*)d_out;

    const int N  = in_sizes[0];
    const int E  = in_sizes[1] / 2;
    const int G  = out_size / OUTC;
    const int EP = E + N;
    const int* esrc = eidx;
    const int* edst = eidx + E;

    // ---- workspace layout ----
    float* bufA    = (float*)d_ws;                     // [N,128] h1, later out3
    float* bufB    = bufA + (size_t)N * DCH;           // [N,128] slot; holds fp16 hproj3
    float* asrc_b  = bufB + (size_t)N * DCH;           // [N,4]
    float* adst_b  = asrc_b + (size_t)N * HEADS;       // [N,4]
    int*   deg     = (int*)(adst_b + (size_t)N * HEADS); // [N] degree, then cursor
    int*   rowstart= deg + N;                          // [N+1]
    int*   bsum    = rowstart + (N + 1);               // [<=1024]
    int*   csr_src = bsum + 1024;                      // [EP]
    int*   gstart  = csr_src + EP;                     // [G+1]
    float* pool    = (float*)(gstart + (G + 1));       // [G,128]
    __half* hp16   = (__half*)bufB;                    // [N,128] fp16

    const int BS = 256;
    const int nb = (N + SCAN_ELEMS - 1) / SCAN_ELEMS;

    // ---- CSR build ----
    hipMemsetAsync(deg, 0, (size_t)N * sizeof(int), stream);
    k_deg<<<(EP + BS - 1) / BS, BS, 0, stream>>>(edst, E, N, deg);
    k_scan_a<<<nb, SCAN_T, 0, stream>>>(deg, rowstart, bsum, N);
    k_scan_b<<<1, 1024, 0, stream>>>(bsum, nb);
    k_scan_c<<<(N + BS - 1) / BS, BS, 0, stream>>>(rowstart, bsum, N);
    hipMemsetAsync(deg, 0, (size_t)N * sizeof(int), stream);   // reuse as cursor
    k_scatter<<<(EP + BS - 1) / BS, BS, 0, stream>>>(esrc, edst, E, N, rowstart, deg, csr_src);

    // ---- conv1 ----
    k_node_att1<<<(N * HEADS + BS - 1) / BS, BS, 0, stream>>>(x, W1, as1, ad1, asrc_b, adst_b, N);
    k_gather1<<<N, DCH, 0, stream>>>(rowstart, csr_src, x, W1, asrc_b, adst_b, b1, bufA, N);

    // ---- conv3 ----
    k_gemm_rb<<<(N + GR - 1) / GR, 256, 0, stream>>>(bufA, W3, hp16, N);
    k_node_att3<<<(N * HEADS + BS - 1) / BS, BS, 0, stream>>>(hp16, as3, ad3, asrc_b, adst_b, N);
    k_gather3<<<N, DCH, 0, stream>>>(rowstart, csr_src, hp16, asrc_b, adst_b, b3, bufA, N);

    // ---- pool + classifier ----
    k_bounds<<<(N + 1 + BS - 1) / BS, BS, 0, stream>>>(batch, gstart, N, G);
    hipMemsetAsync(pool, 0, (size_t)G * DCH * sizeof(float), stream);
    {
        int R = (N + POOL_BLOCKS - 1) / POOL_BLOCKS;
        k_pool_partial<<<POOL_BLOCKS, DCH, 0, stream>>>(bufA, batch, pool, N, R);
    }
    k_final<<<G, DCH, 0, stream>>>(pool, gstart, lw, lb, out, G);
}

// Round 6
// 324.104 us; speedup vs baseline: 6.6788x; 1.1872x over previous
//
#include <hip/hip_runtime.h>
#include <hip/hip_fp16.h>

#define HEADS 4
#define HID 32
#define DCH 128            // HEADS*HID
#define OUTC 10
#define NSLOPE 0.2f

#define SCAN_T 256
#define SCAN_PT 8
#define SCAN_ELEMS (SCAN_T * SCAN_PT)   // 2048 per scan block

#define POOL_BLOCKS 1024
#define CHUNK 32           // edges staged per gather chunk
#define BN 64              // nodes per conv1 block

// ================= CSR build (dst-major) =================
__global__ void k_deg(const int* __restrict__ edst, int E, int N, int* __restrict__ deg) {
    int e = blockIdx.x * blockDim.x + threadIdx.x;
    int EP = E + N;
    if (e >= EP) return;
    int d = (e < E) ? edst[e] : (e - E);     // self-loops appended
    atomicAdd(&deg[d], 1);
}

__global__ void k_scan_a(const int* __restrict__ deg, int* __restrict__ rowstart,
                         int* __restrict__ bsum, int N) {
    __shared__ int sh[SCAN_T];
    int base = blockIdx.x * SCAN_ELEMS;
    int t = threadIdx.x;
    int v[SCAN_PT];
    int s = 0;
#pragma unroll
    for (int i = 0; i < SCAN_PT; i++) {
        int idx = base + t * SCAN_PT + i;
        int dv = (idx < N) ? deg[idx] : 0;
        s += dv; v[i] = s;
    }
    sh[t] = s;
    __syncthreads();
    for (int off = 1; off < SCAN_T; off <<= 1) {
        int add = (t >= off) ? sh[t - off] : 0;
        __syncthreads();
        sh[t] += add;
        __syncthreads();
    }
    int excl = (t > 0) ? sh[t - 1] : 0;
#pragma unroll
    for (int i = 0; i < SCAN_PT; i++) {
        int idx = base + t * SCAN_PT + i;
        if (idx < N) rowstart[idx + 1] = v[i] + excl;
    }
    if (t == SCAN_T - 1) bsum[blockIdx.x] = sh[t];
}

__global__ void k_scan_b(int* __restrict__ bsum, int nb) {
    __shared__ int sh[1024];
    int t = threadIdx.x;
    sh[t] = (t < nb) ? bsum[t] : 0;
    __syncthreads();
    for (int off = 1; off < 1024; off <<= 1) {
        int add = (t >= off) ? sh[t - off] : 0;
        __syncthreads();
        sh[t] += add;
        __syncthreads();
    }
    if (t < nb) bsum[t] = (t > 0) ? sh[t - 1] : 0;
}

__global__ void k_scan_c(int* __restrict__ rowstart, const int* __restrict__ boff, int N) {
    int i = blockIdx.x * blockDim.x + threadIdx.x;
    if (i >= N) return;
    rowstart[i + 1] += boff[i / SCAN_ELEMS];
    if (i == 0) rowstart[0] = 0;
}

__global__ void k_scatter(const int* __restrict__ esrc, const int* __restrict__ edst,
                          int E, int N, const int* __restrict__ rowstart,
                          int* __restrict__ cursor, int* __restrict__ csr_src) {
    int e = blockIdx.x * blockDim.x + threadIdx.x;
    int EP = E + N;
    if (e >= EP) return;
    int s, d;
    if (e < E) { s = esrc[e]; d = edst[e]; } else { s = e - E; d = s; }
    int pos = rowstart[d] + atomicAdd(&cursor[d], 1);
    csr_src[pos] = s;
}

// ================= tables =================
// EXPT2[cd][h*32+cs] = exp(leakyrelu(ts[cs][h] + td[cd][h]))
// was3[h][c] = sum_j W3[c][h*32+j]*att_src3[h][j]  (folded conv3 logit vectors)
__global__ __launch_bounds__(128) void k_tables(
        const float* __restrict__ W1, const float* __restrict__ as1, const float* __restrict__ ad1,
        const float* __restrict__ W3, const float* __restrict__ as3, const float* __restrict__ ad3,
        float* __restrict__ EXPT2, float* __restrict__ was3, float* __restrict__ wad3) {
    __shared__ float ts[32][HEADS], td[32][HEADS];
    int t = threadIdx.x;
    {
        int cs = t >> 2, h = t & 3;
        const float* w = W1 + cs * DCH + h * HID;
        const float* a = as1 + h * HID;
        const float* b = ad1 + h * HID;
        float s1 = 0.f, s2 = 0.f;
#pragma unroll
        for (int j = 0; j < HID; j++) { float wv = w[j]; s1 = fmaf(wv, a[j], s1); s2 = fmaf(wv, b[j], s2); }
        ts[cs][h] = s1; td[cs][h] = s2;
    }
    __syncthreads();
    {
        int h = t >> 5, cs = t & 31;
        for (int cd = 0; cd < 32; cd++) {
            float ev = ts[cs][h] + td[cd][h];
            ev = ev >= 0.f ? ev : NSLOPE * ev;
            EXPT2[cd * DCH + t] = __expf(ev);
        }
    }
    for (int hh = 0; hh < HEADS; hh++) {
        const float* wr = W3 + (size_t)t * DCH + hh * HID;
        const float* a = as3 + hh * HID;
        const float* b = ad3 + hh * HID;
        float s1 = 0.f, s2 = 0.f;
#pragma unroll
        for (int j = 0; j < HID; j++) { float wv = wr[j]; s1 = fmaf(wv, a[j], s1); s2 = fmaf(wv, b[j], s2); }
        was3[hh * DCH + t] = s1; wad3[hh * DCH + t] = s2;
    }
}

// ================= conv1: histogram + table-weighted matvec =================
// h1[d,c] = relu( (sum_k hist_d[k]*EXPT2[x[d]][h*32+k]*W1[k][c]) / den + b1[c] )
__global__ __launch_bounds__(256) void k_conv1(
        const int* __restrict__ rowstart, const int* __restrict__ csr_src,
        const int* __restrict__ x, const float* __restrict__ W1,
        const float* __restrict__ EXPT2, const float* __restrict__ b1,
        __half* __restrict__ h1, int N) {
    __shared__ int   hist[BN][32];
    __shared__ float w[BN][DCH];
    int r0 = blockIdx.x * BN;
    int t = threadIdx.x;
    for (int i = t; i < BN * 32; i += 256) ((int*)hist)[i] = 0;
    __syncthreads();
    {   // 4 threads per node build its class histogram
        int ln = t >> 2, sub = t & 3;
        int node = r0 + ln;
        if (node < N) {
            int p0 = rowstart[node], p1 = rowstart[node + 1];
            for (int p = p0 + sub; p < p1; p += 4)
                atomicAdd(&hist[ln][x[csr_src[p]]], 1);
        }
    }
    __syncthreads();
    for (int i = t; i < BN * DCH; i += 256) {
        int ln = i >> 7, c = i & 127;
        int node = r0 + ln;
        float v = 0.f;
        if (node < N) v = (float)hist[ln][c & 31] * EXPT2[x[node] * DCH + c];
        w[ln][c] = v;
    }
    __syncthreads();
    // GEMM: ct covers cols 4ct..4ct+3 (head h=ct>>3), rt covers 8 rows
    int ct = t & 31, rt = t >> 5;
    int h = ct >> 3;
    float acc[8][4];
    float den[8];
#pragma unroll
    for (int r = 0; r < 8; r++) { den[r] = 0.f;
#pragma unroll
        for (int j = 0; j < 4; j++) acc[r][j] = 0.f; }
    for (int kg = 0; kg < 8; kg++) {
        float wreg[4][4];
#pragma unroll
        for (int kk = 0; kk < 4; kk++) {
            float4 wv = *(const float4*)&W1[(4 * kg + kk) * DCH + 4 * ct];
            wreg[kk][0] = wv.x; wreg[kk][1] = wv.y; wreg[kk][2] = wv.z; wreg[kk][3] = wv.w;
        }
#pragma unroll
        for (int r = 0; r < 8; r++) {
            float4 a4 = *(const float4*)&w[rt * 8 + r][h * 32 + 4 * kg];
            den[r] += a4.x + a4.y + a4.z + a4.w;
            float ar[4] = {a4.x, a4.y, a4.z, a4.w};
#pragma unroll
            for (int kk = 0; kk < 4; kk++)
#pragma unroll
                for (int j = 0; j < 4; j++)
                    acc[r][j] = fmaf(ar[kk], wreg[kk][j], acc[r][j]);
        }
    }
    float4 bb = *(const float4*)&b1[4 * ct];
    float bbv[4] = {bb.x, bb.y, bb.z, bb.w};
#pragma unroll
    for (int r = 0; r < 8; r++) {
        int row = r0 + rt * 8 + r;
        if (row < N) {
            float inv = 1.0f / den[r];
            union { __half hh[4]; uint2 u; } pk;
#pragma unroll
            for (int j = 0; j < 4; j++) {
                float v = acc[r][j] * inv + bbv[j];
                pk.hh[j] = __float2half(v > 0.f ? v : 0.f);
            }
            *(uint2*)&h1[(size_t)row * DCH + 4 * ct] = pk.u;
        }
    }
}

// ================= conv3 logits from folded vectors =================
__global__ __launch_bounds__(256) void k_natt3(
        const __half* __restrict__ h1, const float* __restrict__ was3,
        const float* __restrict__ wad3, float* __restrict__ asrc,
        float* __restrict__ adst, int N) {
    __shared__ float sw[HEADS][DCH], dw[HEADS][DCH];
    int t = threadIdx.x;
    for (int i = t; i < HEADS * DCH; i += 256) { ((float*)sw)[i] = was3[i]; ((float*)dw)[i] = wad3[i]; }
    __syncthreads();
    int n = blockIdx.x * 256 + t;
    if (n >= N) return;
    const __half2* row = (const __half2*)(h1 + (size_t)n * DCH);
    float s[HEADS] = {0.f, 0.f, 0.f, 0.f}, d[HEADS] = {0.f, 0.f, 0.f, 0.f};
    for (int c2 = 0; c2 < DCH / 2; c2++) {
        float2 f = __half22float2(row[c2]);
        int c = 2 * c2;
#pragma unroll
        for (int hh = 0; hh < HEADS; hh++) {
            s[hh] = fmaf(f.x, sw[hh][c], s[hh]);     d[hh] = fmaf(f.x, dw[hh][c], d[hh]);
            s[hh] = fmaf(f.y, sw[hh][c + 1], s[hh]); d[hh] = fmaf(f.y, dw[hh][c + 1], d[hh]);
        }
    }
#pragma unroll
    for (int hh = 0; hh < HEADS; hh++) {
        asrc[n * HEADS + hh] = s[hh];
        adst[n * HEADS + hh] = d[hh];
    }
}

// ================= conv3 gather on h1 (fp16), normalized output z =================
__global__ __launch_bounds__(128) void k_gather3(
        const int* __restrict__ rowstart, const int* __restrict__ csr_src,
        const __half* __restrict__ hp, const float* __restrict__ asrc,
        const float* __restrict__ adst, float* __restrict__ z, int N) {
    __shared__ int   s_sh[CHUNK];
    __shared__ float ex_sh[CHUNK][HEADS];
    __shared__ float accP[4][DCH];
    __shared__ float denP[4][HEADS];
    int d = blockIdx.x;
    int c = threadIdx.x;
    int lane = c & 31, grp = c >> 5;          // lane covers channels 4*lane..4*lane+3
    int myh = lane >> 3;
    int i4 = c >> 2, h4 = c & 3;
    int p0 = rowstart[d], p1 = rowstart[d + 1];
    float a0 = 0.f, a1 = 0.f, a2 = 0.f, a3 = 0.f, den = 0.f;
    for (int base = p0; base < p1; base += CHUNK) {
        int m = p1 - base; if (m > CHUNK) m = CHUNK;
        __syncthreads();
        if (c < m) s_sh[c] = csr_src[base + c];
        __syncthreads();
        if (i4 < m) {
            int s = s_sh[i4];
            float ev = asrc[s * HEADS + h4] + adst[d * HEADS + h4];
            ev = ev >= 0.f ? ev : NSLOPE * ev;
            ex_sh[i4][h4] = __expf(ev);
        }
        __syncthreads();
        for (int i = grp; i < m; i += 4) {
            float ex = ex_sh[i][myh];
            den += ex;
            const uint2 raw = *(const uint2*)(hp + (size_t)s_sh[i] * DCH + lane * 4);
            __half2 h0 = *(const __half2*)&raw.x;
            __half2 h1v = *(const __half2*)&raw.y;
            float2 f0 = __half22float2(h0);
            float2 f1 = __half22float2(h1v);
            a0 = fmaf(ex, f0.x, a0);
            a1 = fmaf(ex, f0.y, a1);
            a2 = fmaf(ex, f1.x, a2);
            a3 = fmaf(ex, f1.y, a3);
        }
    }
    accP[grp][lane * 4 + 0] = a0;
    accP[grp][lane * 4 + 1] = a1;
    accP[grp][lane * 4 + 2] = a2;
    accP[grp][lane * 4 + 3] = a3;
    if ((lane & 7) == 0) denP[grp][myh] = den;
    __syncthreads();
    int hh = c >> 5;
    float a = accP[0][c] + accP[1][c] + accP[2][c] + accP[3][c];
    float dn = denP[0][hh] + denP[1][hh] + denP[2][hh] + denP[3][hh];
    z[(size_t)d * DCH + c] = a / dn;
}

// ---- graph boundaries from sorted batch
__global__ void k_bounds(const int* __restrict__ batch, int* __restrict__ gstart, int N, int G) {
    int n = blockIdx.x * blockDim.x + threadIdx.x;
    if (n > N) return;
    if (n == 0) {
        int b0 = batch[0];
        for (int g = 0; g <= b0; g++) gstart[g] = 0;
        return;
    }
    if (n == N) {
        int bl = batch[N - 1];
        for (int g = bl + 1; g <= G; g++) gstart[g] = N;
        return;
    }
    int b = batch[n], bp = batch[n - 1];
    for (int g = bp + 1; g <= b; g++) gstart[g] = n;
}

// ---- parallel mean-pool over z
__global__ __launch_bounds__(128) void k_pool_partial(
        const float* __restrict__ h, const int* __restrict__ batch,
        float* __restrict__ pool, int N, int R) {
    int c = threadIdx.x;
    int n0 = blockIdx.x * R;
    if (n0 >= N) return;
    int n1 = n0 + R; if (n1 > N) n1 = N;
    float acc = 0.f;
    int curg = batch[n0];
    for (int n = n0; n < n1; n++) {
        int g = batch[n];
        if (g != curg) {
            atomicAdd(&pool[(size_t)curg * DCH + c], acc);
            acc = 0.f; curg = g;
        }
        acc += h[(size_t)n * DCH + c];
    }
    atomicAdd(&pool[(size_t)curg * DCH + c], acc);
}

// ---- pooled @ W3 + b3, then @ lin_w + lin_b
__global__ __launch_bounds__(128) void k_final2(
        const float* __restrict__ pool, const int* __restrict__ gstart,
        const float* __restrict__ W3, const float* __restrict__ b3,
        const float* __restrict__ lw, const float* __restrict__ lb,
        float* __restrict__ out, int G) {
    __shared__ float pooled[DCH];
    __shared__ float t3[DCH];
    int g = blockIdx.x, c = threadIdx.x;
    float cnt = (float)(gstart[g + 1] - gstart[g]);
    pooled[c] = pool[(size_t)g * DCH + c] / fmaxf(cnt, 1.f);
    __syncthreads();
    float acc = b3[c];
#pragma unroll 8
    for (int k = 0; k < DCH; k++) acc = fmaf(pooled[k], W3[k * DCH + c], acc);
    t3[c] = acc;
    __syncthreads();
    if (c < OUTC) {
        float o = lb[c];
#pragma unroll 8
        for (int k = 0; k < DCH; k++) o = fmaf(t3[k], lw[k * OUTC + c], o);
        out[g * OUTC + c] = o;
    }
}

extern "C" void kernel_launch(void* const* d_in, const int* in_sizes, int n_in,
                              void* d_out, int out_size, void* d_ws, size_t ws_size,
                              hipStream_t stream) {
    const int*   x    = (const int*)d_in[0];
    const int*   eidx = (const int*)d_in[1];
    const int*   batch= (const int*)d_in[2];
    const float* W1   = (const float*)d_in[3];
    const float* as1  = (const float*)d_in[4];
    const float* ad1  = (const float*)d_in[5];
    const float* b1   = (const float*)d_in[6];
    const float* W3   = (const float*)d_in[7];
    const float* as3  = (const float*)d_in[8];
    const float* ad3  = (const float*)d_in[9];
    const float* b3   = (const float*)d_in[10];
    const float* lw   = (const float*)d_in[11];
    const float* lb   = (const float*)d_in[12];
    float* out = (float*)d_out;

    const int N  = in_sizes[0];
    const int E  = in_sizes[1] / 2;
    const int G  = out_size / OUTC;
    const int EP = E + N;
    const int* esrc = eidx;
    const int* edst = eidx + E;

    // ---- workspace layout ----
    float*  z       = (float*)d_ws;                       // [N,128] fp32
    __half* h1      = (__half*)(z + (size_t)N * DCH);     // [N,128] fp16
    float*  asrc3   = (float*)(h1 + (size_t)N * DCH);     // [N,4]
    float*  adst3   = asrc3 + (size_t)N * HEADS;          // [N,4]
    int*    deg     = (int*)(adst3 + (size_t)N * HEADS);  // [N]
    int*    rowstart= deg + N;                            // [N+1]
    int*    bsum    = rowstart + (N + 1);                 // [<=1024]
    int*    csr_src = bsum + 1024;                        // [EP]
    int*    gstart  = csr_src + EP;                       // [G+1]
    float*  pool    = (float*)(gstart + (G + 1));         // [G,128]
    float*  EXPT2   = pool + (size_t)G * DCH;             // [32,128]
    float*  was3    = EXPT2 + 32 * DCH;                   // [4,128]
    float*  wad3    = was3 + HEADS * DCH;                 // [4,128]

    const int BS = 256;
    const int nb = (N + SCAN_ELEMS - 1) / SCAN_ELEMS;

    // ---- CSR build ----
    hipMemsetAsync(deg, 0, (size_t)N * sizeof(int), stream);
    k_deg<<<(EP + BS - 1) / BS, BS, 0, stream>>>(edst, E, N, deg);
    k_scan_a<<<nb, SCAN_T, 0, stream>>>(deg, rowstart, bsum, N);
    k_scan_b<<<1, 1024, 0, stream>>>(bsum, nb);
    k_scan_c<<<(N + BS - 1) / BS, BS, 0, stream>>>(rowstart, bsum, N);
    hipMemsetAsync(deg, 0, (size_t)N * sizeof(int), stream);   // cursor
    k_scatter<<<(EP + BS - 1) / BS, BS, 0, stream>>>(esrc, edst, E, N, rowstart, deg, csr_src);

    // ---- tables ----
    k_tables<<<1, 128, 0, stream>>>(W1, as1, ad1, W3, as3, ad3, EXPT2, was3, wad3);

    // ---- conv1 (histogram + table matvec), fp16 h1 ----
    k_conv1<<<(N + BN - 1) / BN, 256, 0, stream>>>(rowstart, csr_src, x, W1, EXPT2, b1, h1, N);

    // ---- conv3 logits + gather on h1 ----
    k_natt3<<<(N + 255) / 256, 256, 0, stream>>>(h1, was3, wad3, asrc3, adst3, N);
    k_gather3<<<N, DCH, 0, stream>>>(rowstart, csr_src, h1, asrc3, adst3, z, N);

    // ---- pool + (W3,b3) + classifier ----
    k_bounds<<<(N + 1 + BS - 1) / BS, BS, 0, stream>>>(batch, gstart, N, G);
    hipMemsetAsync(pool, 0, (size_t)G * DCH * sizeof(float), stream);
    {
        int R = (N + POOL_BLOCKS - 1) / POOL_BLOCKS;
        k_pool_partial<<<POOL_BLOCKS, DCH, 0, stream>>>(z, batch, pool, N, R);
    }
    k_final2<<<G, 128, 0, stream>>>(pool, gstart, W3, b3, lw, lb, out, G);
}